// Round 11
// baseline (382.505 us; speedup 1.0000x reference)
//
#include <hip/hip_runtime.h>

#define H 64
#define CBS 512           // nodes per coarse bucket
#define CB_BITS 9
#define TILE 8192         // edges per partition tile
#define PAD 65            // LDS row stride (floats): 2-way bank aliasing, free
#define CAP 9216          // slab capacity per bucket (mean 8163, sigma 90 -> 11.7 sigma)

// ---------------------------------------------------------------------------
// Init: zero BN stats, seed slab cursors (gcursor[b*16] = b*CAP).
// ---------------------------------------------------------------------------
__global__ void init_kernel(float* __restrict__ stats, int* __restrict__ gcursor, int CB) {
    int t = blockIdx.x * blockDim.x + threadIdx.x;
    if (t < 128) stats[t] = 0.f;
    if (t < CB) gcursor[t * 16] = t * CAP;
}

// ---------------------------------------------------------------------------
// LDS-staged multi-split partition into per-bucket SLABS (no pre-histogram).
// Per 8192-edge tile: LDS hist -> LDS scan -> one slab-cursor atomic per
// (tile,bin) -> bin-sort tile in LDS -> flush bin-ordered.
// pairs[slab pos] = src | (dst&511)<<17.
// ---------------------------------------------------------------------------
__global__ __launch_bounds__(256)
void part_staged_kernel(const int* __restrict__ ei, int* __restrict__ gcursor,
                        int* __restrict__ pairs, int E, int N, int CB) {
    __shared__ int sd[256];
    __shared__ int excl[256];
    __shared__ int gbase[256];
    __shared__ int lcur[256];
    __shared__ int stage[TILE];
    __shared__ unsigned char bin8[TILE];
    int t = threadIdx.x;
    int ntiles = (E + TILE - 1) / TILE;
    for (int tile = blockIdx.x; tile < ntiles; tile += gridDim.x) {
        int base = tile * TILE;
        int cnt = min(TILE, E - base);
        sd[t] = 0;
        __syncthreads();
        for (int i = t; i < cnt; i += 256) {
            int s = ei[base + i];
            int d = ei[E + base + i];
            if ((unsigned)s < (unsigned)N && (unsigned)d < (unsigned)N)
                atomicAdd(&sd[d >> CB_BITS], 1);
        }
        __syncthreads();
        int v = sd[t];
        __syncthreads();
        for (int off = 1; off < 256; off <<= 1) {
            int add = (t >= off) ? sd[t - off] : 0;
            __syncthreads();
            sd[t] += add;
            __syncthreads();
        }
        int ex = sd[t] - v;
        excl[t] = ex;
        lcur[t] = ex;
        if (t < CB && v > 0) gbase[t] = atomicAdd(&gcursor[t * 16], v);
        int tot = sd[255];
        __syncthreads();
        for (int i = t; i < cnt; i += 256) {
            int s = ei[base + i];
            int d = ei[E + base + i];
            if ((unsigned)s < (unsigned)N && (unsigned)d < (unsigned)N) {
                int cb = d >> CB_BITS;
                int pos = atomicAdd(&lcur[cb], 1);
                stage[pos] = s | ((d & (CBS - 1)) << 17);
                bin8[pos] = (unsigned char)cb;
            }
        }
        __syncthreads();
        for (int i = t; i < tot; i += 256) {
            int b8 = bin8[i];
            pairs[gbase[b8] + (i - excl[b8])] = stage[i];
        }
        __syncthreads();
    }
}

// ---------------------------------------------------------------------------
// Tiny scan over CB bucket counts (from final slab cursors) -> compact global
// CSR bases gbb[0..CB]; also writes rowptr[N] = E-valid total.
// ---------------------------------------------------------------------------
__global__ __launch_bounds__(256)
void scan_cb_kernel(const int* __restrict__ gcursor, int* __restrict__ gbb,
                    int* __restrict__ rowptr, int CB, int N) {
    __shared__ int sd[256];
    int t = threadIdx.x;
    int cnt = (t < CB) ? (gcursor[t * 16] - t * CAP) : 0;
    sd[t] = cnt; __syncthreads();
    for (int off = 1; off < 256; off <<= 1) {
        int add = (t >= off) ? sd[t - off] : 0;
        __syncthreads();
        sd[t] += add;
        __syncthreads();
    }
    if (t < CB) gbb[t] = sd[t] - cnt;
    if (t == 0) { gbb[CB] = sd[255]; rowptr[N] = sd[255]; }
}

// ---------------------------------------------------------------------------
// Per-bucket fine CSR from slab -> globally compact ebuf + rowptr.
// ---------------------------------------------------------------------------
__global__ __launch_bounds__(256)
void bucket_csr_kernel(const int* __restrict__ pairs, const int* __restrict__ gcursor,
                       const int* __restrict__ gbb,
                       int* __restrict__ ebuf, int* __restrict__ rowptr, int N) {
    __shared__ int hist[CBS];
    __shared__ int cur[CBS];
    __shared__ int sd[256];
    __shared__ int carry_s;
    int b = blockIdx.x;
    int t = threadIdx.x;
    int pb = b * CAP;
    int cnt = gcursor[b * 16] - pb;
    int gb = gbb[b];
    for (int i = t; i < CBS; i += 256) hist[i] = 0;
    if (t == 0) carry_s = 0;
    __syncthreads();
    for (int i = t; i < cnt; i += 256)
        atomicAdd(&hist[(pairs[pb + i] >> 17) & (CBS - 1)], 1);
    __syncthreads();
    for (int start = 0; start < CBS; start += 256) {
        int v = hist[start + t];
        sd[t] = v; __syncthreads();
        for (int off = 1; off < 256; off <<= 1) {
            int add = (t >= off) ? sd[t - off] : 0;
            __syncthreads();
            sd[t] += add;
            __syncthreads();
        }
        int ex = sd[t] - v + carry_s;
        cur[start + t] = ex;
        int node = b * CBS + start + t;
        if (node < N) rowptr[node] = gb + ex;
        __syncthreads();
        if (t == 0) carry_s += sd[255];
        __syncthreads();
    }
    for (int i = t; i < cnt; i += 256) {
        int p = pairs[pb + i];
        int pos = atomicAdd(&cur[(p >> 17) & (CBS - 1)], 1);
        ebuf[gb + pos] = p & 0x1FFFF;
    }
}

// ---------------------------------------------------------------------------
// Fold linear head:  (relu(z)@W2b + b2b)@LW + LB == relu(z)@Wf + bf
// ---------------------------------------------------------------------------
__global__ void fold_head_kernel(const float* __restrict__ W2b, const float* __restrict__ B2b,
                                 const float* __restrict__ LW, const float* __restrict__ LB,
                                 float* __restrict__ Wf, float* __restrict__ bf) {
    int t = blockIdx.x * blockDim.x + threadIdx.x;
    if (t < 640) {
        int k = t / 10, c = t % 10;
        float a = 0.f;
        for (int m = 0; m < H; ++m) a = fmaf(W2b[k * H + m], LW[m * 10 + c], a);
        Wf[t] = a;
    } else if (t < 650) {
        int c = t - 640;
        float a = LB[c];
        for (int m = 0; m < H; ++m) a = fmaf(B2b[m], LW[m * 10 + c], a);
        bf[c] = a;
    }
}

// ---------------------------------------------------------------------------
// Layer-1 gather: wave per node, 8-wide unguarded main loop + remainder.
// ---------------------------------------------------------------------------
__global__ __launch_bounds__(256)
void gather1_kernel(const float* __restrict__ x, const int* __restrict__ rowptr,
                    const int* __restrict__ ebuf, float* __restrict__ bufA, int N) {
    int wid = (int)(((long long)blockIdx.x * blockDim.x + threadIdx.x) >> 6);
    int lane = threadIdx.x & 63;
    if (wid >= N) return;
    int p0 = __builtin_amdgcn_readfirstlane(rowptr[wid]);
    int pe = __builtin_amdgcn_readfirstlane(rowptr[wid + 1]);
    float acc = x[((long long)wid << 6) + lane];
    int nfull = (pe - p0) & ~7;
    int p = p0;
    for (; p < p0 + nfull; p += 8) {
        float v0 = x[((long long)ebuf[p + 0] << 6) + lane];
        float v1 = x[((long long)ebuf[p + 1] << 6) + lane];
        float v2 = x[((long long)ebuf[p + 2] << 6) + lane];
        float v3 = x[((long long)ebuf[p + 3] << 6) + lane];
        float v4 = x[((long long)ebuf[p + 4] << 6) + lane];
        float v5 = x[((long long)ebuf[p + 5] << 6) + lane];
        float v6 = x[((long long)ebuf[p + 6] << 6) + lane];
        float v7 = x[((long long)ebuf[p + 7] << 6) + lane];
        acc += ((v0 + v1) + (v2 + v3)) + ((v4 + v5) + (v6 + v7));
    }
    for (; p < pe; ++p) acc += x[((long long)ebuf[p] << 6) + lane];
    bufA[((long long)wid << 6) + lane] = acc;
}

// ---------------------------------------------------------------------------
// Layer-2 gather with self row and full folded BN:
//   bufC = scale*(h1[self] + sum_j h1[j]) + (deg+1)*shift
// ---------------------------------------------------------------------------
__global__ __launch_bounds__(256)
void gather2_kernel(const float* __restrict__ h1p, const float* __restrict__ scale,
                    const float* __restrict__ shiftv, const int* __restrict__ rowptr,
                    const int* __restrict__ ebuf, float* __restrict__ bufC, int N) {
    int wid = (int)(((long long)blockIdx.x * blockDim.x + threadIdx.x) >> 6);
    int lane = threadIdx.x & 63;
    if (wid >= N) return;
    int p0 = __builtin_amdgcn_readfirstlane(rowptr[wid]);
    int pe = __builtin_amdgcn_readfirstlane(rowptr[wid + 1]);
    float acc = h1p[((long long)wid << 6) + lane];   // self
    int nfull = (pe - p0) & ~7;
    int p = p0;
    for (; p < p0 + nfull; p += 8) {
        float v0 = h1p[((long long)ebuf[p + 0] << 6) + lane];
        float v1 = h1p[((long long)ebuf[p + 1] << 6) + lane];
        float v2 = h1p[((long long)ebuf[p + 2] << 6) + lane];
        float v3 = h1p[((long long)ebuf[p + 3] << 6) + lane];
        float v4 = h1p[((long long)ebuf[p + 4] << 6) + lane];
        float v5 = h1p[((long long)ebuf[p + 5] << 6) + lane];
        float v6 = h1p[((long long)ebuf[p + 6] << 6) + lane];
        float v7 = h1p[((long long)ebuf[p + 7] << 6) + lane];
        acc += ((v0 + v1) + (v2 + v3)) + ((v4 + v5) + (v6 + v7));
    }
    for (; p < pe; ++p) acc += h1p[((long long)ebuf[p] << 6) + lane];
    float degp1 = (float)(pe - p0 + 1);
    bufC[((long long)wid << 6) + lane] = acc * scale[lane] + degp1 * shiftv[lane];
}

// ---------------------------------------------------------------------------
// MLP layer 1 + fused BN stats, WAVE-SLICE layout:
// block = 256 threads = 4 waves handles a 64-node tile (one LDS tile, 19 KB
// -> 8 blocks/CU = 32 waves/CU). Thread (wv,lane): node = lane, output slice
// j in [wv*16, wv*16+16). Weight slice is wave-uniform -> s_load_dwordx16.
// ReLU intermediate round-trips through the same tile.
// ---------------------------------------------------------------------------
__global__ __launch_bounds__(256)
void mlp1_kernel(const float* __restrict__ bufA, float* __restrict__ h1p,
                 const float* __restrict__ W1a, const float* __restrict__ B1a,
                 const float* __restrict__ W1b, const float* __restrict__ B1b,
                 float* __restrict__ stats, int N) {
    __shared__ float S[64 * PAD];        // 16.64 KB
    __shared__ float red[2][4][64];      // 2 KB
    int t = threadIdx.x, wv = t >> 6, lane = t & 63;
    int node0 = blockIdx.x * 64;
    int q16 = __builtin_amdgcn_readfirstlane(wv * 16);

    // stage 64 rows, coalesced (zero rows beyond N)
    for (int i = t; i < 4096; i += 256) {
        int r = i >> 6, c = i & 63;
        float v = 0.f;
        if (node0 + r < N) v = bufA[((long long)(node0 + r) << 6) + c];
        S[r * PAD + c] = v;
    }
    __syncthreads();

    float u[16];
#pragma unroll
    for (int j = 0; j < 16; ++j) u[j] = B1a[q16 + j];
#pragma unroll 1
    for (int k = 0; k < H; ++k) {
        float hk = S[lane * PAD + k];
        const float* wr = W1a + k * H + q16;
#pragma unroll
        for (int j = 0; j < 16; ++j) u[j] = fmaf(hk, wr[j], u[j]);
    }
    __syncthreads();
#pragma unroll
    for (int j = 0; j < 16; ++j) S[lane * PAD + q16 + j] = fmaxf(u[j], 0.f);
    __syncthreads();

    float h1v[16];
#pragma unroll
    for (int j = 0; j < 16; ++j) h1v[j] = B1b[q16 + j];
#pragma unroll 1
    for (int k = 0; k < H; ++k) {
        float uk = S[lane * PAD + k];
        const float* wr = W1b + k * H + q16;
#pragma unroll
        for (int j = 0; j < 16; ++j) h1v[j] = fmaf(uk, wr[j], h1v[j]);
    }
    __syncthreads();
    bool valid = (node0 + lane < N);
#pragma unroll
    for (int j = 0; j < 16; ++j) S[lane * PAD + q16 + j] = valid ? h1v[j] : 0.f;
    __syncthreads();

    // coalesced h1p store
    for (int i = t; i < 4096; i += 256) {
        int r = i >> 6, c = i & 63;
        if (node0 + r < N)
            h1p[((long long)(node0 + r) << 6) + c] = S[r * PAD + c];
    }
    // BN stats: wave wv sums its 16 rows, lane = feature
    float s = 0.f, s2 = 0.f;
#pragma unroll
    for (int r = 0; r < 16; ++r) {
        float v = S[(q16 + r) * PAD + lane];
        s += v;
        s2 = fmaf(v, v, s2);
    }
    red[0][wv][lane] = s;
    red[1][wv][lane] = s2;
    __syncthreads();
    if (wv == 0) {
        float ts  = (red[0][0][lane] + red[0][1][lane]) + (red[0][2][lane] + red[0][3][lane]);
        float ts2 = (red[1][0][lane] + red[1][1][lane]) + (red[1][2][lane] + red[1][3][lane]);
        unsafeAtomicAdd(&stats[lane], ts);
        unsafeAtomicAdd(&stats[H + lane], ts2);
    }
}

__global__ void bn_finalize_kernel(const float* __restrict__ stats,
                                   const float* __restrict__ gamma,
                                   const float* __restrict__ beta,
                                   float* __restrict__ scale, float* __restrict__ shiftv, float n) {
    int f = threadIdx.x;
    if (f >= H) return;
    float mean = stats[f] / n;
    float var = stats[H + f] / n - mean * mean;   // biased, matches jnp.var
    var = fmaxf(var, 0.f);
    float s = gamma[f] * rsqrtf(var + 1e-5f);
    scale[f] = s;
    shiftv[f] = beta[f] - mean * s;
}

// ---------------------------------------------------------------------------
// MLP layer 2 + folded head, wave-slice layout. GEMM-1 as mlp1; the thin
// 64->10 head is split-K across the 4 waves (k-slice of 16) + LDS reduce.
// ---------------------------------------------------------------------------
__global__ __launch_bounds__(256)
void mlp2_kernel(const float* __restrict__ bufC,
                 const float* __restrict__ W2a, const float* __restrict__ B2a,
                 const float* __restrict__ Wf, const float* __restrict__ bf,
                 float* __restrict__ out, int N) {
    __shared__ float S[64 * PAD];        // 16.64 KB
    __shared__ float Op[4][640];         // 10.24 KB partials
    int t = threadIdx.x, wv = t >> 6, lane = t & 63;
    int node0 = blockIdx.x * 64;
    int q16 = __builtin_amdgcn_readfirstlane(wv * 16);

    for (int i = t; i < 4096; i += 256) {
        int r = i >> 6, c = i & 63;
        float v = 0.f;
        if (node0 + r < N) v = bufC[((long long)(node0 + r) << 6) + c];
        S[r * PAD + c] = v;
    }
    __syncthreads();

    float u[16];
#pragma unroll
    for (int j = 0; j < 16; ++j) u[j] = B2a[q16 + j];
#pragma unroll 1
    for (int k = 0; k < H; ++k) {
        float hk = S[lane * PAD + k];
        const float* wr = W2a + k * H + q16;
#pragma unroll
        for (int j = 0; j < 16; ++j) u[j] = fmaf(hk, wr[j], u[j]);
    }
    __syncthreads();
#pragma unroll
    for (int j = 0; j < 16; ++j) S[lane * PAD + q16 + j] = fmaxf(u[j], 0.f);
    __syncthreads();

    // split-K head: wave wv covers k in [q16, q16+16)
    float o[10];
#pragma unroll
    for (int c = 0; c < 10; ++c) o[c] = 0.f;
#pragma unroll 1
    for (int kk = 0; kk < 16; ++kk) {
        float uk = S[lane * PAD + q16 + kk];
        const float* wr = Wf + (q16 + kk) * 10;
#pragma unroll
        for (int c = 0; c < 10; ++c) o[c] = fmaf(uk, wr[c], o[c]);
    }
#pragma unroll
    for (int c = 0; c < 10; ++c) Op[wv][lane * 10 + c] = o[c];
    __syncthreads();
    for (int i = t; i < 640; i += 256) {
        int r = i / 10, c = i - r * 10;
        if (node0 + r < N) {
            float val = bf[c] + ((Op[0][i] + Op[1][i]) + (Op[2][i] + Op[3][i]));
            out[(long long)(node0 + r) * 10 + c] = val;
        }
    }
}

extern "C" void kernel_launch(void* const* d_in, const int* in_sizes, int n_in,
                              void* d_out, int out_size, void* d_ws, size_t ws_size,
                              hipStream_t stream) {
    const float* x    = (const float*)d_in[0];
    const int*   ei   = (const int*)d_in[1];
    const float* w1a  = (const float*)d_in[2];
    const float* b1a  = (const float*)d_in[3];
    const float* w1b  = (const float*)d_in[4];
    const float* b1b  = (const float*)d_in[5];
    const float* bng  = (const float*)d_in[6];
    const float* bnb  = (const float*)d_in[7];
    const float* w2a  = (const float*)d_in[8];
    const float* b2a  = (const float*)d_in[9];
    const float* w2b  = (const float*)d_in[10];
    const float* b2b  = (const float*)d_in[11];
    const float* linw = (const float*)d_in[12];
    const float* linb = (const float*)d_in[13];

    int N = in_sizes[0] / H;       // 100000
    int E = in_sizes[1] / 2;       // 1600000
    int CB = (N + CBS - 1) / CBS;  // 196 coarse buckets

    // ---- workspace layout (pairs slab aliases bufC: lifetimes disjoint) ----
    float* ws     = (float*)d_ws;
    float* bufA   = ws;                          // N*H: agg1 -> h1p in place
    float* bufC   = ws + (size_t)N * H;          // N*H: full layer-2 input
    int*   pairs  = (int*)bufC;                  // CB*CAP slab (dead before gather2)
    float* stats  = ws + 2 * (size_t)N * H;      // 128
    float* scale  = stats + 128;                 // 64
    float* shiftv = stats + 192;                 // 64
    float* Wf     = stats + 256;                 // 640
    float* bf     = Wf + 640;                    // 16
    int*   gcursor= (int*)(bf + 16);             // 256*16 (64B-padded cursors)
    int*   gbb    = gcursor + 256 * 16;          // CB+1
    int*   rowptr = gbb + 257;                   // N+1
    int*   ebuf   = rowptr + (N + 1);            // E

    int ntiles = (E + TILE - 1) / TILE;

    init_kernel<<<1, 256, 0, stream>>>(stats, gcursor, CB);
    part_staged_kernel<<<ntiles, 256, 0, stream>>>(ei, gcursor, pairs, E, N, CB);
    scan_cb_kernel<<<1, 256, 0, stream>>>(gcursor, gbb, rowptr, CB, N);
    bucket_csr_kernel<<<CB, 256, 0, stream>>>(pairs, gcursor, gbb, ebuf, rowptr, N);
    fold_head_kernel<<<3, 256, 0, stream>>>(w2b, b2b, linw, linb, Wf, bf);

    int gblocks = (int)(((long long)N * 64 + 255) / 256);
    int mblocks = (N + 63) / 64;
    gather1_kernel<<<gblocks, 256, 0, stream>>>(x, rowptr, ebuf, bufA, N);
    mlp1_kernel<<<mblocks, 256, 0, stream>>>(bufA, bufA, w1a, b1a, w1b, b1b, stats, N);
    bn_finalize_kernel<<<1, 64, 0, stream>>>(stats, bng, bnb, scale, shiftv, (float)N);

    gather2_kernel<<<gblocks, 256, 0, stream>>>(bufA, scale, shiftv, rowptr, ebuf, bufC, N);
    mlp2_kernel<<<mblocks, 256, 0, stream>>>(bufC, w2a, b2a, Wf, bf, (float*)d_out, N);
}

// Round 12
// 374.090 us; speedup vs baseline: 1.0225x; 1.0225x over previous
//
#include <hip/hip_runtime.h>
#include <hip/hip_fp16.h>

#define H 64
#define CBS 512           // nodes per coarse bucket
#define CB_BITS 9
#define TILE 8192         // edges per partition tile
#define PAD 65            // LDS row stride (floats): 2-way bank aliasing, free
#define CAP 9216          // slab capacity per bucket (mean 8192, sigma 90 -> 11 sigma)

// ---------------------------------------------------------------------------
// Init: zero BN stats, seed slab cursors.
// ---------------------------------------------------------------------------
__global__ void init_kernel(float* __restrict__ stats, int* __restrict__ gcursor, int CB) {
    int t = blockIdx.x * blockDim.x + threadIdx.x;
    if (t < 128) stats[t] = 0.f;
    if (t < CB) gcursor[t * 16] = t * CAP;
}

// x (fp32) -> xh (fp16), vectorized.
__global__ __launch_bounds__(256)
void cvt_x_kernel(const float* __restrict__ x, __half* __restrict__ xh, int total4) {
    int i = blockIdx.x * blockDim.x + threadIdx.x;
    if (i >= total4) return;
    float4 v = ((const float4*)x)[i];
    __half h0 = __float2half(v.x), h1 = __float2half(v.y);
    __half h2 = __float2half(v.z), h3 = __float2half(v.w);
    ushort4 pk;
    pk.x = *(unsigned short*)&h0; pk.y = *(unsigned short*)&h1;
    pk.z = *(unsigned short*)&h2; pk.w = *(unsigned short*)&h3;
    ((ushort4*)xh)[i] = pk;
}

// ---------------------------------------------------------------------------
// LDS-staged multi-split partition into per-bucket slabs (R11-proven).
// ---------------------------------------------------------------------------
__global__ __launch_bounds__(256)
void part_staged_kernel(const int* __restrict__ ei, int* __restrict__ gcursor,
                        int* __restrict__ pairs, int E, int N, int CB) {
    __shared__ int sd[256];
    __shared__ int excl[256];
    __shared__ int gbase[256];
    __shared__ int lcur[256];
    __shared__ int stage[TILE];
    __shared__ unsigned char bin8[TILE];
    int t = threadIdx.x;
    int ntiles = (E + TILE - 1) / TILE;
    for (int tile = blockIdx.x; tile < ntiles; tile += gridDim.x) {
        int base = tile * TILE;
        int cnt = min(TILE, E - base);
        sd[t] = 0;
        __syncthreads();
        for (int i = t; i < cnt; i += 256) {
            int s = ei[base + i];
            int d = ei[E + base + i];
            if ((unsigned)s < (unsigned)N && (unsigned)d < (unsigned)N)
                atomicAdd(&sd[d >> CB_BITS], 1);
        }
        __syncthreads();
        int v = sd[t];
        __syncthreads();
        for (int off = 1; off < 256; off <<= 1) {
            int add = (t >= off) ? sd[t - off] : 0;
            __syncthreads();
            sd[t] += add;
            __syncthreads();
        }
        int ex = sd[t] - v;
        excl[t] = ex;
        lcur[t] = ex;
        if (t < CB && v > 0) gbase[t] = atomicAdd(&gcursor[t * 16], v);
        int tot = sd[255];
        __syncthreads();
        for (int i = t; i < cnt; i += 256) {
            int s = ei[base + i];
            int d = ei[E + base + i];
            if ((unsigned)s < (unsigned)N && (unsigned)d < (unsigned)N) {
                int cb = d >> CB_BITS;
                int pos = atomicAdd(&lcur[cb], 1);
                stage[pos] = s | ((d & (CBS - 1)) << 17);
                bin8[pos] = (unsigned char)cb;
            }
        }
        __syncthreads();
        for (int i = t; i < tot; i += 256) {
            int b8 = bin8[i];
            pairs[gbase[b8] + (i - excl[b8])] = stage[i];
        }
        __syncthreads();
    }
}

__global__ __launch_bounds__(256)
void scan_cb_kernel(const int* __restrict__ gcursor, int* __restrict__ gbb,
                    int* __restrict__ rowptr, int CB, int N) {
    __shared__ int sd[256];
    int t = threadIdx.x;
    int cnt = (t < CB) ? (gcursor[t * 16] - t * CAP) : 0;
    sd[t] = cnt; __syncthreads();
    for (int off = 1; off < 256; off <<= 1) {
        int add = (t >= off) ? sd[t - off] : 0;
        __syncthreads();
        sd[t] += add;
        __syncthreads();
    }
    if (t < CB) gbb[t] = sd[t] - cnt;
    if (t == 0) { gbb[CB] = sd[255]; rowptr[N] = sd[255]; }
}

__global__ __launch_bounds__(256)
void bucket_csr_kernel(const int* __restrict__ pairs, const int* __restrict__ gcursor,
                       const int* __restrict__ gbb,
                       int* __restrict__ ebuf, int* __restrict__ rowptr, int N) {
    __shared__ int hist[CBS];
    __shared__ int cur[CBS];
    __shared__ int sd[256];
    __shared__ int carry_s;
    int b = blockIdx.x;
    int t = threadIdx.x;
    int pb = b * CAP;
    int cnt = gcursor[b * 16] - pb;
    int gb = gbb[b];
    for (int i = t; i < CBS; i += 256) hist[i] = 0;
    if (t == 0) carry_s = 0;
    __syncthreads();
    for (int i = t; i < cnt; i += 256)
        atomicAdd(&hist[(pairs[pb + i] >> 17) & (CBS - 1)], 1);
    __syncthreads();
    for (int start = 0; start < CBS; start += 256) {
        int v = hist[start + t];
        sd[t] = v; __syncthreads();
        for (int off = 1; off < 256; off <<= 1) {
            int add = (t >= off) ? sd[t - off] : 0;
            __syncthreads();
            sd[t] += add;
            __syncthreads();
        }
        int ex = sd[t] - v + carry_s;
        cur[start + t] = ex;
        int node = b * CBS + start + t;
        if (node < N) rowptr[node] = gb + ex;
        __syncthreads();
        if (t == 0) carry_s += sd[255];
        __syncthreads();
    }
    for (int i = t; i < cnt; i += 256) {
        int p = pairs[pb + i];
        int pos = atomicAdd(&cur[(p >> 17) & (CBS - 1)], 1);
        ebuf[gb + pos] = p & 0x1FFFF;
    }
}

// ---------------------------------------------------------------------------
// Fold linear head:  (relu(z)@W2b + b2b)@LW + LB == relu(z)@Wf + bf
// ---------------------------------------------------------------------------
__global__ void fold_head_kernel(const float* __restrict__ W2b, const float* __restrict__ B2b,
                                 const float* __restrict__ LW, const float* __restrict__ LB,
                                 float* __restrict__ Wf, float* __restrict__ bf) {
    int t = blockIdx.x * blockDim.x + threadIdx.x;
    if (t < 640) {
        int k = t / 10, c = t % 10;
        float a = 0.f;
        for (int m = 0; m < H; ++m) a = fmaf(W2b[k * H + m], LW[m * 10 + c], a);
        Wf[t] = a;
    } else if (t < 650) {
        int c = t - 640;
        float a = LB[c];
        for (int m = 0; m < H; ++m) a = fmaf(B2b[m], LW[m * 10 + c], a);
        bf[c] = a;
    }
}

// ---------------------------------------------------------------------------
// Layer-1 gather over fp16 rows (128 B/row): wave per node, 8-wide ILP.
// fp32 accumulate; fp16 store.
// ---------------------------------------------------------------------------
__global__ __launch_bounds__(256)
void gather1_kernel(const __half* __restrict__ xh, const int* __restrict__ rowptr,
                    const int* __restrict__ ebuf, __half* __restrict__ bufA, int N) {
    int wid = (int)(((long long)blockIdx.x * blockDim.x + threadIdx.x) >> 6);
    int lane = threadIdx.x & 63;
    if (wid >= N) return;
    int p0 = __builtin_amdgcn_readfirstlane(rowptr[wid]);
    int pe = __builtin_amdgcn_readfirstlane(rowptr[wid + 1]);
    float acc = __half2float(xh[((long long)wid << 6) + lane]);
    int nfull = (pe - p0) & ~7;
    int p = p0;
    for (; p < p0 + nfull; p += 8) {
        float v0 = __half2float(xh[((long long)ebuf[p + 0] << 6) + lane]);
        float v1 = __half2float(xh[((long long)ebuf[p + 1] << 6) + lane]);
        float v2 = __half2float(xh[((long long)ebuf[p + 2] << 6) + lane]);
        float v3 = __half2float(xh[((long long)ebuf[p + 3] << 6) + lane]);
        float v4 = __half2float(xh[((long long)ebuf[p + 4] << 6) + lane]);
        float v5 = __half2float(xh[((long long)ebuf[p + 5] << 6) + lane]);
        float v6 = __half2float(xh[((long long)ebuf[p + 6] << 6) + lane]);
        float v7 = __half2float(xh[((long long)ebuf[p + 7] << 6) + lane]);
        acc += ((v0 + v1) + (v2 + v3)) + ((v4 + v5) + (v6 + v7));
    }
    for (; p < pe; ++p) acc += __half2float(xh[((long long)ebuf[p] << 6) + lane]);
    bufA[((long long)wid << 6) + lane] = __float2half(acc);
}

// ---------------------------------------------------------------------------
// Layer-2 gather (fp16 h1p rows) with self term and full folded BN:
//   bufC = scale*(h1[self] + sum_j h1[j]) + (deg+1)*shift      (fp16 out)
// ---------------------------------------------------------------------------
__global__ __launch_bounds__(256)
void gather2_kernel(const __half* __restrict__ h1p, const float* __restrict__ scale,
                    const float* __restrict__ shiftv, const int* __restrict__ rowptr,
                    const int* __restrict__ ebuf, __half* __restrict__ bufC, int N) {
    int wid = (int)(((long long)blockIdx.x * blockDim.x + threadIdx.x) >> 6);
    int lane = threadIdx.x & 63;
    if (wid >= N) return;
    int p0 = __builtin_amdgcn_readfirstlane(rowptr[wid]);
    int pe = __builtin_amdgcn_readfirstlane(rowptr[wid + 1]);
    float acc = __half2float(h1p[((long long)wid << 6) + lane]);   // self
    int nfull = (pe - p0) & ~7;
    int p = p0;
    for (; p < p0 + nfull; p += 8) {
        float v0 = __half2float(h1p[((long long)ebuf[p + 0] << 6) + lane]);
        float v1 = __half2float(h1p[((long long)ebuf[p + 1] << 6) + lane]);
        float v2 = __half2float(h1p[((long long)ebuf[p + 2] << 6) + lane]);
        float v3 = __half2float(h1p[((long long)ebuf[p + 3] << 6) + lane]);
        float v4 = __half2float(h1p[((long long)ebuf[p + 4] << 6) + lane]);
        float v5 = __half2float(h1p[((long long)ebuf[p + 5] << 6) + lane]);
        float v6 = __half2float(h1p[((long long)ebuf[p + 6] << 6) + lane]);
        float v7 = __half2float(h1p[((long long)ebuf[p + 7] << 6) + lane]);
        acc += ((v0 + v1) + (v2 + v3)) + ((v4 + v5) + (v6 + v7));
    }
    for (; p < pe; ++p) acc += __half2float(h1p[((long long)ebuf[p] << 6) + lane]);
    float degp1 = (float)(pe - p0 + 1);
    bufC[((long long)wid << 6) + lane] = __float2half(acc * scale[lane] + degp1 * shiftv[lane]);
}

// ---------------------------------------------------------------------------
// MLP layer 1 + fused BN stats (R10-proven structure: thread-per-node, rolled
// k-loops, relu intermediate via own LDS row). fp16 global I/O, fp32 compute.
// ---------------------------------------------------------------------------
__global__ __launch_bounds__(256)
void mlp1_kernel(const __half* __restrict__ bufA, __half* __restrict__ h1p,
                 const float* __restrict__ W1a, const float* __restrict__ B1a,
                 const float* __restrict__ W1b, const float* __restrict__ B1b,
                 float* __restrict__ stats, int N) {
    __shared__ float st[4][64 * PAD];     // 66.56 KB
    __shared__ float red[2][4][64];
    int t = threadIdx.x, wv = t >> 6, lane = t & 63;
    int node0 = (blockIdx.x * 4 + wv) * 64;
    float* S = st[wv];

#pragma unroll 8
    for (int r = 0; r < 64; ++r) {
        float v = 0.f;
        if (node0 + r < N) v = __half2float(bufA[((long long)(node0 + r) << 6) + lane]);
        S[r * PAD + lane] = v;
    }
    bool valid = (node0 + lane < N);

    float u[H];
#pragma unroll
    for (int j = 0; j < H; ++j) u[j] = B1a[j];
#pragma unroll 1
    for (int k = 0; k < H; ++k) {
        float hk = S[lane * PAD + k];
#pragma unroll
        for (int j = 0; j < H; ++j) u[j] = fmaf(hk, W1a[k * H + j], u[j]);
    }
#pragma unroll
    for (int j = 0; j < H; ++j) S[lane * PAD + j] = fmaxf(u[j], 0.f);

    float h1[H];
#pragma unroll
    for (int j = 0; j < H; ++j) h1[j] = B1b[j];
#pragma unroll 1
    for (int k = 0; k < H; ++k) {
        float uk = S[lane * PAD + k];
#pragma unroll
        for (int j = 0; j < H; ++j) h1[j] = fmaf(uk, W1b[k * H + j], h1[j]);
    }
#pragma unroll
    for (int j = 0; j < H; ++j) S[lane * PAD + j] = valid ? h1[j] : 0.f;

#pragma unroll 8
    for (int r = 0; r < 64; ++r) {
        if (node0 + r < N)
            h1p[((long long)(node0 + r) << 6) + lane] = __float2half(S[r * PAD + lane]);
    }
    float s = 0.f, s2 = 0.f;
#pragma unroll 8
    for (int r = 0; r < 64; ++r) {
        float v = S[r * PAD + lane];
        s += v;
        s2 = fmaf(v, v, s2);
    }
    red[0][wv][lane] = s;
    red[1][wv][lane] = s2;
    __syncthreads();
    if (wv == 0) {
        float ts  = (red[0][0][lane] + red[0][1][lane]) + (red[0][2][lane] + red[0][3][lane]);
        float ts2 = (red[1][0][lane] + red[1][1][lane]) + (red[1][2][lane] + red[1][3][lane]);
        unsafeAtomicAdd(&stats[lane], ts);
        unsafeAtomicAdd(&stats[H + lane], ts2);
    }
}

__global__ void bn_finalize_kernel(const float* __restrict__ stats,
                                   const float* __restrict__ gamma,
                                   const float* __restrict__ beta,
                                   float* __restrict__ scale, float* __restrict__ shiftv, float n) {
    int f = threadIdx.x;
    if (f >= H) return;
    float mean = stats[f] / n;
    float var = stats[H + f] / n - mean * mean;   // biased, matches jnp.var
    var = fmaxf(var, 0.f);
    float s = gamma[f] * rsqrtf(var + 1e-5f);
    scale[f] = s;
    shiftv[f] = beta[f] - mean * s;
}

// ---------------------------------------------------------------------------
// MLP layer 2 + folded head (fp16 in, fp32 out), R10 structure.
// ---------------------------------------------------------------------------
__global__ __launch_bounds__(256)
void mlp2_kernel(const __half* __restrict__ bufC,
                 const float* __restrict__ W2a, const float* __restrict__ B2a,
                 const float* __restrict__ Wf, const float* __restrict__ bf,
                 float* __restrict__ out, int N) {
    __shared__ float st[4][64 * PAD];     // 66.56 KB
    __shared__ float ost[4][64 * 11];     // 11.26 KB
    int t = threadIdx.x, wv = t >> 6, lane = t & 63;
    int node0 = (blockIdx.x * 4 + wv) * 64;
    float* S = st[wv];
    float* O = ost[wv];

#pragma unroll 8
    for (int r = 0; r < 64; ++r) {
        float v = 0.f;
        if (node0 + r < N) v = __half2float(bufC[((long long)(node0 + r) << 6) + lane]);
        S[r * PAD + lane] = v;
    }
    float u[H];
#pragma unroll
    for (int j = 0; j < H; ++j) u[j] = B2a[j];
#pragma unroll 1
    for (int k = 0; k < H; ++k) {
        float hk = S[lane * PAD + k];
#pragma unroll
        for (int j = 0; j < H; ++j) u[j] = fmaf(hk, W2a[k * H + j], u[j]);
    }
#pragma unroll
    for (int j = 0; j < H; ++j) S[lane * PAD + j] = fmaxf(u[j], 0.f);

    float o[10];
#pragma unroll
    for (int c = 0; c < 10; ++c) o[c] = bf[c];
#pragma unroll 1
    for (int k = 0; k < H; ++k) {
        float uk = S[lane * PAD + k];
#pragma unroll
        for (int c = 0; c < 10; ++c) o[c] = fmaf(uk, Wf[k * 10 + c], o[c]);
    }
#pragma unroll
    for (int c = 0; c < 10; ++c) O[lane * 11 + c] = o[c];
    for (int i = lane; i < 640; i += 64) {
        int r = i / 10, c = i - r * 10;
        if (node0 + r < N)
            out[(long long)(node0 + r) * 10 + c] = O[r * 11 + c];
    }
}

extern "C" void kernel_launch(void* const* d_in, const int* in_sizes, int n_in,
                              void* d_out, int out_size, void* d_ws, size_t ws_size,
                              hipStream_t stream) {
    const float* x    = (const float*)d_in[0];
    const int*   ei   = (const int*)d_in[1];
    const float* w1a  = (const float*)d_in[2];
    const float* b1a  = (const float*)d_in[3];
    const float* w1b  = (const float*)d_in[4];
    const float* b1b  = (const float*)d_in[5];
    const float* bng  = (const float*)d_in[6];
    const float* bnb  = (const float*)d_in[7];
    const float* w2a  = (const float*)d_in[8];
    const float* b2a  = (const float*)d_in[9];
    const float* w2b  = (const float*)d_in[10];
    const float* b2b  = (const float*)d_in[11];
    const float* linw = (const float*)d_in[12];
    const float* linb = (const float*)d_in[13];

    int N = in_sizes[0] / H;       // 100000
    int E = in_sizes[1] / 2;       // 1600000
    int CB = (N + CBS - 1) / CBS;  // 196 coarse buckets

    // ---- workspace layout (all fp16 intermediates) ----
    size_t NH = (size_t)N * H;
    char*  wsb    = (char*)d_ws;
    __half* xh    = (__half*)wsb;                        // NH fp16
    __half* bufA  = (__half*)(wsb + NH * 2);             // NH fp16 (agg1 -> h1p in place)
    __half* bufC  = (__half*)(wsb + NH * 4);             // NH fp16
    float* stats  = (float*)(wsb + NH * 6);              // 128
    float* scale  = stats + 128;                         // 64
    float* shiftv = stats + 192;                         // 64
    float* Wf     = stats + 256;                         // 640
    float* bf     = Wf + 640;                            // 16
    int*   gcursor= (int*)(bf + 16);                     // 256*16
    int*   gbb    = gcursor + 256 * 16;                  // CB+1
    int*   rowptr = gbb + 257;                           // N+1
    int*   ebuf   = rowptr + (N + 1);                    // E
    int*   pairs  = ebuf + E;                            // CB*CAP slab

    int ntiles = (E + TILE - 1) / TILE;

    init_kernel<<<1, 256, 0, stream>>>(stats, gcursor, CB);
    cvt_x_kernel<<<(int)((NH / 4 + 255) / 256), 256, 0, stream>>>(x, xh, (int)(NH / 4));
    part_staged_kernel<<<ntiles, 256, 0, stream>>>(ei, gcursor, pairs, E, N, CB);
    scan_cb_kernel<<<1, 256, 0, stream>>>(gcursor, gbb, rowptr, CB, N);
    bucket_csr_kernel<<<CB, 256, 0, stream>>>(pairs, gcursor, gbb, ebuf, rowptr, N);
    fold_head_kernel<<<3, 256, 0, stream>>>(w2b, b2b, linw, linb, Wf, bf);

    int gblocks = (int)(((long long)N * 64 + 255) / 256);
    int mblocks = (N + 255) / 256;
    gather1_kernel<<<gblocks, 256, 0, stream>>>(xh, rowptr, ebuf, bufA, N);
    mlp1_kernel<<<mblocks, 256, 0, stream>>>(bufA, bufA, w1a, b1a, w1b, b1b, stats, N);
    bn_finalize_kernel<<<1, 64, 0, stream>>>(stats, bng, bnb, scale, shiftv, (float)N);

    gather2_kernel<<<gblocks, 256, 0, stream>>>(bufA, scale, shiftv, rowptr, ebuf, bufC, N);
    mlp2_kernel<<<mblocks, 256, 0, stream>>>(bufC, w2a, b2a, Wf, bf, (float*)d_out, N);
}

// Round 13
// 311.607 us; speedup vs baseline: 1.2275x; 1.2005x over previous
//
#include <hip/hip_runtime.h>
#include <hip/hip_fp16.h>

#define H 64
#define CBS 512           // nodes per coarse bucket
#define CB_BITS 9
#define TILE 8192         // edges per partition tile
#define CAP 9216          // slab capacity per bucket

typedef _Float16 f16;
typedef __attribute__((ext_vector_type(8))) _Float16 v8h;
typedef __attribute__((ext_vector_type(4))) float v4f;

// ---------------------------------------------------------------------------
// Init: zero BN stats, seed slab cursors.
// ---------------------------------------------------------------------------
__global__ void init_kernel(float* __restrict__ stats, int* __restrict__ gcursor, int CB) {
    int t = blockIdx.x * blockDim.x + threadIdx.x;
    if (t < 128) stats[t] = 0.f;
    if (t < CB) gcursor[t * 16] = t * CAP;
}

// x (fp32) -> xh (fp16), vectorized.
__global__ __launch_bounds__(256)
void cvt_x_kernel(const float* __restrict__ x, f16* __restrict__ xh, int total4) {
    int i = blockIdx.x * blockDim.x + threadIdx.x;
    if (i >= total4) return;
    float4 v = ((const float4*)x)[i];
    f16 h0 = (f16)v.x, h1 = (f16)v.y, h2 = (f16)v.z, h3 = (f16)v.w;
    ushort4 pk;
    pk.x = *(unsigned short*)&h0; pk.y = *(unsigned short*)&h1;
    pk.z = *(unsigned short*)&h2; pk.w = *(unsigned short*)&h3;
    ((ushort4*)xh)[i] = pk;
}

// ---------------------------------------------------------------------------
// LDS-staged multi-split partition into per-bucket slabs (R11-proven).
// ---------------------------------------------------------------------------
__global__ __launch_bounds__(256)
void part_staged_kernel(const int* __restrict__ ei, int* __restrict__ gcursor,
                        int* __restrict__ pairs, int E, int N, int CB) {
    __shared__ int sd[256];
    __shared__ int excl[256];
    __shared__ int gbase[256];
    __shared__ int lcur[256];
    __shared__ int stage[TILE];
    __shared__ unsigned char bin8[TILE];
    int t = threadIdx.x;
    int ntiles = (E + TILE - 1) / TILE;
    for (int tile = blockIdx.x; tile < ntiles; tile += gridDim.x) {
        int base = tile * TILE;
        int cnt = min(TILE, E - base);
        sd[t] = 0;
        __syncthreads();
        for (int i = t; i < cnt; i += 256) {
            int s = ei[base + i];
            int d = ei[E + base + i];
            if ((unsigned)s < (unsigned)N && (unsigned)d < (unsigned)N)
                atomicAdd(&sd[d >> CB_BITS], 1);
        }
        __syncthreads();
        int v = sd[t];
        __syncthreads();
        for (int off = 1; off < 256; off <<= 1) {
            int add = (t >= off) ? sd[t - off] : 0;
            __syncthreads();
            sd[t] += add;
            __syncthreads();
        }
        int ex = sd[t] - v;
        excl[t] = ex;
        lcur[t] = ex;
        if (t < CB && v > 0) gbase[t] = atomicAdd(&gcursor[t * 16], v);
        int tot = sd[255];
        __syncthreads();
        for (int i = t; i < cnt; i += 256) {
            int s = ei[base + i];
            int d = ei[E + base + i];
            if ((unsigned)s < (unsigned)N && (unsigned)d < (unsigned)N) {
                int cb = d >> CB_BITS;
                int pos = atomicAdd(&lcur[cb], 1);
                stage[pos] = s | ((d & (CBS - 1)) << 17);
                bin8[pos] = (unsigned char)cb;
            }
        }
        __syncthreads();
        for (int i = t; i < tot; i += 256) {
            int b8 = bin8[i];
            pairs[gbase[b8] + (i - excl[b8])] = stage[i];
        }
        __syncthreads();
    }
}

__global__ __launch_bounds__(256)
void scan_cb_kernel(const int* __restrict__ gcursor, int* __restrict__ gbb,
                    int* __restrict__ rowptr, int CB, int N) {
    __shared__ int sd[256];
    int t = threadIdx.x;
    int cnt = (t < CB) ? (gcursor[t * 16] - t * CAP) : 0;
    sd[t] = cnt; __syncthreads();
    for (int off = 1; off < 256; off <<= 1) {
        int add = (t >= off) ? sd[t - off] : 0;
        __syncthreads();
        sd[t] += add;
        __syncthreads();
    }
    if (t < CB) gbb[t] = sd[t] - cnt;
    if (t == 0) { gbb[CB] = sd[255]; rowptr[N] = sd[255]; }
}

__global__ __launch_bounds__(256)
void bucket_csr_kernel(const int* __restrict__ pairs, const int* __restrict__ gcursor,
                       const int* __restrict__ gbb,
                       int* __restrict__ ebuf, int* __restrict__ rowptr, int N) {
    __shared__ int hist[CBS];
    __shared__ int cur[CBS];
    __shared__ int sd[256];
    __shared__ int carry_s;
    int b = blockIdx.x;
    int t = threadIdx.x;
    int pb = b * CAP;
    int cnt = gcursor[b * 16] - pb;
    int gb = gbb[b];
    for (int i = t; i < CBS; i += 256) hist[i] = 0;
    if (t == 0) carry_s = 0;
    __syncthreads();
    for (int i = t; i < cnt; i += 256)
        atomicAdd(&hist[(pairs[pb + i] >> 17) & (CBS - 1)], 1);
    __syncthreads();
    for (int start = 0; start < CBS; start += 256) {
        int v = hist[start + t];
        sd[t] = v; __syncthreads();
        for (int off = 1; off < 256; off <<= 1) {
            int add = (t >= off) ? sd[t - off] : 0;
            __syncthreads();
            sd[t] += add;
            __syncthreads();
        }
        int ex = sd[t] - v + carry_s;
        cur[start + t] = ex;
        int node = b * CBS + start + t;
        if (node < N) rowptr[node] = gb + ex;
        __syncthreads();
        if (t == 0) carry_s += sd[255];
        __syncthreads();
    }
    for (int i = t; i < cnt; i += 256) {
        int p = pairs[pb + i];
        int pos = atomicAdd(&cur[(p >> 17) & (CBS - 1)], 1);
        ebuf[gb + pos] = p & 0x1FFFF;
    }
}

// ---------------------------------------------------------------------------
// Fold linear head (fp32):  (relu(z)@W2b + b2b)@LW + LB == relu(z)@Wf + bf
// ---------------------------------------------------------------------------
__global__ void fold_head_kernel(const float* __restrict__ W2b, const float* __restrict__ B2b,
                                 const float* __restrict__ LW, const float* __restrict__ LB,
                                 float* __restrict__ Wf, float* __restrict__ bf) {
    int t = blockIdx.x * blockDim.x + threadIdx.x;
    if (t < 640) {
        int k = t / 10, c = t % 10;
        float a = 0.f;
        for (int m = 0; m < H; ++m) a = fmaf(W2b[k * H + m], LW[m * 10 + c], a);
        Wf[t] = a;
    } else if (t < 650) {
        int c = t - 640;
        float a = LB[c];
        for (int m = 0; m < H; ++m) a = fmaf(B2b[m], LW[m * 10 + c], a);
        bf[c] = a;
    }
}

// ---------------------------------------------------------------------------
// Repack weights into fp16 MFMA B-fragment order:
//   pk[((nt*2+ks)*64 + lane)*8 + j] = W[ks*32 + ((lane>>4)&3)*8 + j][nt*16 + (lane&15)]
// pkf likewise for the 64x10 folded head (cols 10..15 zero-padded).
// ---------------------------------------------------------------------------
__global__ void repack_kernel(const float* __restrict__ W1a, const float* __restrict__ W1b,
                              const float* __restrict__ W2a, const float* __restrict__ Wf,
                              f16* __restrict__ pk1a, f16* __restrict__ pk1b,
                              f16* __restrict__ pk2a, f16* __restrict__ pkf) {
    int t = blockIdx.x * blockDim.x + threadIdx.x;
    if (t < 12288) {
        int m = t >> 12;
        int e = t & 4095;
        int j = e & 7, lane = (e >> 3) & 63, ks = (e >> 9) & 1, nt = e >> 10;
        int row = ks * 32 + ((lane >> 4) & 3) * 8 + j;
        int col = nt * 16 + (lane & 15);
        const float* W = (m == 0) ? W1a : (m == 1) ? W1b : W2a;
        f16* P = (m == 0) ? pk1a : (m == 1) ? pk1b : pk2a;
        P[e] = (f16)W[row * 64 + col];
    } else if (t < 13312) {
        int e = t - 12288;
        int j = e & 7, lane = (e >> 3) & 63, ks = e >> 9;
        int row = ks * 32 + ((lane >> 4) & 3) * 8 + j;
        int col = lane & 15;
        pkf[e] = (col < 10) ? (f16)Wf[row * 10 + col] : (f16)0;
    }
}

// ---------------------------------------------------------------------------
// Layer-1 gather over fp16 rows: wave per node, 8-wide ILP (R12-proven).
// ---------------------------------------------------------------------------
__global__ __launch_bounds__(256)
void gather1_kernel(const f16* __restrict__ xh, const int* __restrict__ rowptr,
                    const int* __restrict__ ebuf, f16* __restrict__ bufA, int N) {
    int wid = (int)(((long long)blockIdx.x * blockDim.x + threadIdx.x) >> 6);
    int lane = threadIdx.x & 63;
    if (wid >= N) return;
    int p0 = __builtin_amdgcn_readfirstlane(rowptr[wid]);
    int pe = __builtin_amdgcn_readfirstlane(rowptr[wid + 1]);
    float acc = (float)xh[((long long)wid << 6) + lane];
    int nfull = (pe - p0) & ~7;
    int p = p0;
    for (; p < p0 + nfull; p += 8) {
        float v0 = (float)xh[((long long)ebuf[p + 0] << 6) + lane];
        float v1 = (float)xh[((long long)ebuf[p + 1] << 6) + lane];
        float v2 = (float)xh[((long long)ebuf[p + 2] << 6) + lane];
        float v3 = (float)xh[((long long)ebuf[p + 3] << 6) + lane];
        float v4 = (float)xh[((long long)ebuf[p + 4] << 6) + lane];
        float v5 = (float)xh[((long long)ebuf[p + 5] << 6) + lane];
        float v6 = (float)xh[((long long)ebuf[p + 6] << 6) + lane];
        float v7 = (float)xh[((long long)ebuf[p + 7] << 6) + lane];
        acc += ((v0 + v1) + (v2 + v3)) + ((v4 + v5) + (v6 + v7));
    }
    for (; p < pe; ++p) acc += (float)xh[((long long)ebuf[p] << 6) + lane];
    bufA[((long long)wid << 6) + lane] = (f16)acc;
}

// ---------------------------------------------------------------------------
// Layer-2 gather with self term and full folded BN (fp16 in/out).
// ---------------------------------------------------------------------------
__global__ __launch_bounds__(256)
void gather2_kernel(const f16* __restrict__ h1p, const float* __restrict__ scale,
                    const float* __restrict__ shiftv, const int* __restrict__ rowptr,
                    const int* __restrict__ ebuf, f16* __restrict__ bufC, int N) {
    int wid = (int)(((long long)blockIdx.x * blockDim.x + threadIdx.x) >> 6);
    int lane = threadIdx.x & 63;
    if (wid >= N) return;
    int p0 = __builtin_amdgcn_readfirstlane(rowptr[wid]);
    int pe = __builtin_amdgcn_readfirstlane(rowptr[wid + 1]);
    float acc = (float)h1p[((long long)wid << 6) + lane];   // self
    int nfull = (pe - p0) & ~7;
    int p = p0;
    for (; p < p0 + nfull; p += 8) {
        float v0 = (float)h1p[((long long)ebuf[p + 0] << 6) + lane];
        float v1 = (float)h1p[((long long)ebuf[p + 1] << 6) + lane];
        float v2 = (float)h1p[((long long)ebuf[p + 2] << 6) + lane];
        float v3 = (float)h1p[((long long)ebuf[p + 3] << 6) + lane];
        float v4 = (float)h1p[((long long)ebuf[p + 4] << 6) + lane];
        float v5 = (float)h1p[((long long)ebuf[p + 5] << 6) + lane];
        float v6 = (float)h1p[((long long)ebuf[p + 6] << 6) + lane];
        float v7 = (float)h1p[((long long)ebuf[p + 7] << 6) + lane];
        acc += ((v0 + v1) + (v2 + v3)) + ((v4 + v5) + (v6 + v7));
    }
    for (; p < pe; ++p) acc += (float)h1p[((long long)ebuf[p] << 6) + lane];
    float degp1 = (float)(pe - p0 + 1);
    bufC[((long long)wid << 6) + lane] = (f16)(acc * scale[lane] + degp1 * shiftv[lane]);
}

// ---------------------------------------------------------------------------
// MFMA MLP layer 1 + fused BN stats.
// Block = 4 waves, 64-node tile; wave w owns nodes [node0+w*16, +16).
// GEMM = 2 K-steps x 4 N-tiles of mfma_f32_16x16x32_f16 (8 MFMA per GEMM).
// A-frags: A[m=lane&15][k=quad*8+j]; C: col=lane&15, row=quad*4+reg.
// relu intermediate staged in LDS (stride 72 halves -> 2-way banks, free).
// ---------------------------------------------------------------------------
__global__ __launch_bounds__(256)
void mlp1_kernel(const f16* __restrict__ bufA, f16* __restrict__ h1p,
                 const f16* __restrict__ pk1a, const f16* __restrict__ pk1b,
                 const float* __restrict__ B1a, const float* __restrict__ B1b,
                 float* __restrict__ stats, int N) {
    __shared__ f16 Su[4][16 * 72];
    __shared__ f16 Sh[4][16 * 72];
    __shared__ float red[2][4][64];
    int t = threadIdx.x, wv = t >> 6, lane = t & 63;
    int quad = lane >> 4, r16 = lane & 15;
    int node0 = blockIdx.x * 64 + wv * 16;
    int nodeA = node0 + r16;

    v8h a0 = {}, a1 = {};
    if (nodeA < N) {
        a0 = *(const v8h*)(bufA + (size_t)nodeA * 64 + quad * 8);
        a1 = *(const v8h*)(bufA + (size_t)nodeA * 64 + 32 + quad * 8);
    }
#pragma unroll
    for (int nt = 0; nt < 4; ++nt) {
        v8h b0 = *(const v8h*)(pk1a + (((nt * 2 + 0) * 64 + lane) << 3));
        v8h b1 = *(const v8h*)(pk1a + (((nt * 2 + 1) * 64 + lane) << 3));
        v4f c = {0.f, 0.f, 0.f, 0.f};
        c = __builtin_amdgcn_mfma_f32_16x16x32_f16(a0, b0, c, 0, 0, 0);
        c = __builtin_amdgcn_mfma_f32_16x16x32_f16(a1, b1, c, 0, 0, 0);
        float bias = B1a[nt * 16 + r16];
#pragma unroll
        for (int reg = 0; reg < 4; ++reg)
            Su[wv][(quad * 4 + reg) * 72 + nt * 16 + r16] = (f16)fmaxf(c[reg] + bias, 0.f);
    }
    __syncthreads();
    v8h u0 = *(const v8h*)(&Su[wv][r16 * 72 + quad * 8]);
    v8h u1 = *(const v8h*)(&Su[wv][r16 * 72 + 32 + quad * 8]);
#pragma unroll
    for (int nt = 0; nt < 4; ++nt) {
        v8h b0 = *(const v8h*)(pk1b + (((nt * 2 + 0) * 64 + lane) << 3));
        v8h b1 = *(const v8h*)(pk1b + (((nt * 2 + 1) * 64 + lane) << 3));
        v4f c = {0.f, 0.f, 0.f, 0.f};
        c = __builtin_amdgcn_mfma_f32_16x16x32_f16(u0, b0, c, 0, 0, 0);
        c = __builtin_amdgcn_mfma_f32_16x16x32_f16(u1, b1, c, 0, 0, 0);
        float bias = B1b[nt * 16 + r16];
#pragma unroll
        for (int reg = 0; reg < 4; ++reg) {
            int row = quad * 4 + reg;
            bool valid = (node0 + row) < N;
            Sh[wv][row * 72 + nt * 16 + r16] = valid ? (f16)(c[reg] + bias) : (f16)0;
        }
    }
    __syncthreads();
    for (int i = lane; i < 1024; i += 64) {
        int row = i >> 6, col = i & 63;
        int node = node0 + row;
        if (node < N) h1p[(size_t)node * 64 + col] = Sh[wv][row * 72 + col];
    }
    float s = 0.f, s2 = 0.f;
#pragma unroll
    for (int row = 0; row < 16; ++row) {
        float v = (float)Sh[wv][row * 72 + lane];
        s += v;
        s2 = fmaf(v, v, s2);
    }
    red[0][wv][lane] = s;
    red[1][wv][lane] = s2;
    __syncthreads();
    if (wv == 0) {
        float ts  = (red[0][0][lane] + red[0][1][lane]) + (red[0][2][lane] + red[0][3][lane]);
        float ts2 = (red[1][0][lane] + red[1][1][lane]) + (red[1][2][lane] + red[1][3][lane]);
        unsafeAtomicAdd(&stats[lane], ts);
        unsafeAtomicAdd(&stats[64 + lane], ts2);
    }
}

__global__ void bn_finalize_kernel(const float* __restrict__ stats,
                                   const float* __restrict__ gamma,
                                   const float* __restrict__ beta,
                                   float* __restrict__ scale, float* __restrict__ shiftv, float n) {
    int f = threadIdx.x;
    if (f >= H) return;
    float mean = stats[f] / n;
    float var = stats[H + f] / n - mean * mean;   // biased, matches jnp.var
    var = fmaxf(var, 0.f);
    float s = gamma[f] * rsqrtf(var + 1e-5f);
    scale[f] = s;
    shiftv[f] = beta[f] - mean * s;
}

// ---------------------------------------------------------------------------
// MFMA MLP layer 2 + folded head: GEMM1 as mlp1; head is a single N-tile
// (cols 0..9 valid, 10..15 zero-padded in pkf) -> direct fp32 store.
// ---------------------------------------------------------------------------
__global__ __launch_bounds__(256)
void mlp2_kernel(const f16* __restrict__ bufC,
                 const f16* __restrict__ pk2a, const f16* __restrict__ pkf,
                 const float* __restrict__ B2a, const float* __restrict__ bf,
                 float* __restrict__ out, int N) {
    __shared__ f16 Su[4][16 * 72];
    int t = threadIdx.x, wv = t >> 6, lane = t & 63;
    int quad = lane >> 4, r16 = lane & 15;
    int node0 = blockIdx.x * 64 + wv * 16;
    int nodeA = node0 + r16;

    v8h a0 = {}, a1 = {};
    if (nodeA < N) {
        a0 = *(const v8h*)(bufC + (size_t)nodeA * 64 + quad * 8);
        a1 = *(const v8h*)(bufC + (size_t)nodeA * 64 + 32 + quad * 8);
    }
#pragma unroll
    for (int nt = 0; nt < 4; ++nt) {
        v8h b0 = *(const v8h*)(pk2a + (((nt * 2 + 0) * 64 + lane) << 3));
        v8h b1 = *(const v8h*)(pk2a + (((nt * 2 + 1) * 64 + lane) << 3));
        v4f c = {0.f, 0.f, 0.f, 0.f};
        c = __builtin_amdgcn_mfma_f32_16x16x32_f16(a0, b0, c, 0, 0, 0);
        c = __builtin_amdgcn_mfma_f32_16x16x32_f16(a1, b1, c, 0, 0, 0);
        float bias = B2a[nt * 16 + r16];
#pragma unroll
        for (int reg = 0; reg < 4; ++reg)
            Su[wv][(quad * 4 + reg) * 72 + nt * 16 + r16] = (f16)fmaxf(c[reg] + bias, 0.f);
    }
    __syncthreads();
    v8h u0 = *(const v8h*)(&Su[wv][r16 * 72 + quad * 8]);
    v8h u1 = *(const v8h*)(&Su[wv][r16 * 72 + 32 + quad * 8]);
    v8h b0 = *(const v8h*)(pkf + ((0 * 64 + lane) << 3));
    v8h b1 = *(const v8h*)(pkf + ((1 * 64 + lane) << 3));
    v4f c = {0.f, 0.f, 0.f, 0.f};
    c = __builtin_amdgcn_mfma_f32_16x16x32_f16(u0, b0, c, 0, 0, 0);
    c = __builtin_amdgcn_mfma_f32_16x16x32_f16(u1, b1, c, 0, 0, 0);
    if (r16 < 10) {
        float bias = bf[r16];
#pragma unroll
        for (int reg = 0; reg < 4; ++reg) {
            int node = node0 + quad * 4 + reg;
            if (node < N) out[(size_t)node * 10 + r16] = c[reg] + bias;
        }
    }
}

extern "C" void kernel_launch(void* const* d_in, const int* in_sizes, int n_in,
                              void* d_out, int out_size, void* d_ws, size_t ws_size,
                              hipStream_t stream) {
    const float* x    = (const float*)d_in[0];
    const int*   ei   = (const int*)d_in[1];
    const float* w1a  = (const float*)d_in[2];
    const float* b1a  = (const float*)d_in[3];
    const float* w1b  = (const float*)d_in[4];
    const float* b1b  = (const float*)d_in[5];
    const float* bng  = (const float*)d_in[6];
    const float* bnb  = (const float*)d_in[7];
    const float* w2a  = (const float*)d_in[8];
    const float* b2a  = (const float*)d_in[9];
    const float* w2b  = (const float*)d_in[10];
    const float* b2b  = (const float*)d_in[11];
    const float* linw = (const float*)d_in[12];
    const float* linb = (const float*)d_in[13];

    int N = in_sizes[0] / H;       // 100000
    int E = in_sizes[1] / 2;       // 1600000
    int CB = (N + CBS - 1) / CBS;  // 196 coarse buckets

    // ---- workspace layout ----
    size_t NH = (size_t)N * H;
    char*  wsb    = (char*)d_ws;
    f16*   xh     = (f16*)wsb;                           // NH fp16
    f16*   bufA   = (f16*)(wsb + NH * 2);                // NH fp16 (agg1 -> h1p in place)
    f16*   bufC   = (f16*)(wsb + NH * 4);                // NH fp16
    float* stats  = (float*)(wsb + NH * 6);              // 128
    float* scale  = stats + 128;                         // 64
    float* shiftv = stats + 192;                         // 64
    float* Wf     = stats + 256;                         // 640
    float* bf     = Wf + 640;                            // 16
    f16*   pk1a   = (f16*)(bf + 16);                     // 4096 (16B-aligned)
    f16*   pk1b   = pk1a + 4096;
    f16*   pk2a   = pk1b + 4096;
    f16*   pkf    = pk2a + 4096;                         // 1024
    int*   gcursor= (int*)(pkf + 1024);                  // 256*16
    int*   gbb    = gcursor + 256 * 16;                  // CB+1
    int*   rowptr = gbb + 257;                           // N+1
    int*   ebuf   = rowptr + (N + 1);                    // E
    int*   pairs  = ebuf + E;                            // CB*CAP slab

    int ntiles = (E + TILE - 1) / TILE;

    init_kernel<<<1, 256, 0, stream>>>(stats, gcursor, CB);
    cvt_x_kernel<<<(int)((NH / 4 + 255) / 256), 256, 0, stream>>>(x, xh, (int)(NH / 4));
    part_staged_kernel<<<ntiles, 256, 0, stream>>>(ei, gcursor, pairs, E, N, CB);
    scan_cb_kernel<<<1, 256, 0, stream>>>(gcursor, gbb, rowptr, CB, N);
    bucket_csr_kernel<<<CB, 256, 0, stream>>>(pairs, gcursor, gbb, ebuf, rowptr, N);
    fold_head_kernel<<<3, 256, 0, stream>>>(w2b, b2b, linw, linb, Wf, bf);
    repack_kernel<<<(13312 + 255) / 256, 256, 0, stream>>>(w1a, w1b, w2a, Wf,
                                                           pk1a, pk1b, pk2a, pkf);

    int gblocks = (int)(((long long)N * 64 + 255) / 256);
    int mblocks = (N + 63) / 64;
    gather1_kernel<<<gblocks, 256, 0, stream>>>(xh, rowptr, ebuf, bufA, N);
    mlp1_kernel<<<mblocks, 256, 0, stream>>>(bufA, bufA, pk1a, pk1b, b1a, b1b, stats, N);
    bn_finalize_kernel<<<1, 64, 0, stream>>>(stats, bng, bnb, scale, shiftv, (float)N);

    gather2_kernel<<<gblocks, 256, 0, stream>>>(bufA, scale, shiftv, rowptr, ebuf, bufC, N);
    mlp2_kernel<<<mblocks, 256, 0, stream>>>(bufC, pk2a, pkf, b2a, bf, (float*)d_out, N);
}